// Round 1
// baseline (324.087 us; speedup 1.0000x reference)
//
#include <hip/hip_runtime.h>
#include <stdint.h>

#define BATCH 8192   // Gram K dimension
#define DIM   2048   // Gram M and N
#define NT    272    // symmetric tiles: 136 per Gram x 2 Grams
#define QTOT  (NT * 32)        // 8704 (tile, k-iter) work items
#define QPB   17               // 8704 / 512 blocks, exact

typedef unsigned char  u8;
typedef unsigned short u16;
typedef unsigned int   u32;

using v8i   = __attribute__((ext_vector_type(8)))  int;
using v16f  = __attribute__((ext_vector_type(16))) float;
using f32x4 = __attribute__((ext_vector_type(4)))  float;

#if __has_builtin(__builtin_amdgcn_cvt_scalef32_pk_fp4_f32)
#define HW_FP4 1
#endif

// async global->LDS, 16B per lane; dest must be wave-uniform base + lane*16.
__device__ __forceinline__ void gl_lds16(const void* g, void* l) {
  __builtin_amdgcn_global_load_lds(
      (const __attribute__((address_space(1))) u32*)g,
      (__attribute__((address_space(3))) u32*)l, 16, 0, 0);
}

// Fallback f32 -> fp4 e2m1 nibble of (64*x), round-to-nearest.
__device__ __forceinline__ u32 nib4(float x) {
  float xs = x * 64.0f;
  float a  = fabsf(xs);
  u32 n = (u32)(a >= 0.25f) + (u32)(a >= 0.75f) + (u32)(a >= 1.25f) +
          (u32)(a >= 1.75f) + (u32)(a >= 2.5f)  + (u32)(a >= 3.5f)  +
          (u32)(a >= 5.0f);
  return n | (xs < 0.0f ? 8u : 0u);
}

// Pack 4 floats (quant domain = 64*x) into 4 e2m1 nibbles (u16).
__device__ __forceinline__ u16 pack4_fp4(float a, float b, float c, float d) {
#ifdef HW_FP4
  u32 w = __builtin_amdgcn_cvt_scalef32_pk_fp4_f32(0u,  a * 64.0f, b * 64.0f, 1.0f, 0);
  w     = __builtin_amdgcn_cvt_scalef32_pk_fp4_f32(w,   c * 64.0f, d * 64.0f, 1.0f, 1);
  return (u16)w;   // nibble-order differences are k-permutations -> cancel
#else
  return (u16)(nib4(a) | (nib4(b) << 4) | (nib4(c) << 8) | (nib4(d) << 12));
#endif
}

// ---------------------------------------------------------------------------
// Kernel 1: fused transpose + f32->fp4. src [8192 b][2048 d] f32 ->
// dst [2048 d][8192 b-fp4] (4096 B/row).
// Round-9 changes: (a) loads kept in registers via ext_vector + constant
// subscripts only (round-8's &f[j][0] pointer array defeated SROA ->
// VGPR_Count=32, loads never actually hoisted); 2-deep pipeline (8 loads
// in flight, VGPR budget <=64 keeps 8 blocks/CU). (b) zero-inits the
// compact Gram buffer Gc for gram's atomic accumulation.
// ---------------------------------------------------------------------------
__global__ __launch_bounds__(256) void tcvt_fp4(
    const float* __restrict__ L, const float* __restrict__ T,
    u8* __restrict__ X, u8* __restrict__ Y,
    float* __restrict__ Gc, float* __restrict__ acc, u32* __restrict__ cnt)
{
  __shared__ u16 ls[64 * 68];   // [d][64 u16 payload + 4 pad]

  const int tid = threadIdx.x;
  if (blockIdx.x == 0 && tid == 0) { *acc = 0.0f; *cnt = 0u; }

  { // zero Gc (272 tiles * 16384 f = 17.8 MB); grid-stride float4 stores
    const float4 z = {0.f, 0.f, 0.f, 0.f};
    for (int i = blockIdx.x * 256 + tid; i < NT * 4096; i += 2048 * 256)
      ((float4*)Gc)[i] = z;
  }

  int id = blockIdx.x;
  const float* src;
  u8* dst;
  if (id < 1024) { src = L; dst = X; }
  else           { src = T; dst = Y; id -= 1024; }
  const int d0 = (id & 31) * 64;
  const int b0 = (id >> 5) * 256;

  const int s  = tid & 15;          // d-slot (d = 4s..4s+3)
  const int g  = tid >> 4;          // b row-group
  const int sw = s & 12;

  const float* base = src + (size_t)(b0 + g * 4) * DIM + d0 + s * 4;

  // 2-deep pipeline: load j-group j+1 while packing j-group j.
  f32x4 f[2][4];
#pragma unroll
  for (int r = 0; r < 4; ++r)
    f[0][r] = *(const f32x4*)(base + (size_t)r * DIM);

#pragma unroll
  for (int j = 0; j < 4; ++j) {
    if (j < 3) {
#pragma unroll
      for (int r = 0; r < 4; ++r)
        f[(j + 1) & 1][r] = *(const f32x4*)(base + (size_t)((j + 1) * 64 + r) * DIM);
    }
    const int w = (j * 16 + g) ^ sw;   // u16 column 0..63
#pragma unroll
    for (int i = 0; i < 4; ++i)
      ls[(s * 4 + i) * 68 + w] =
          pack4_fp4(f[j & 1][0][i], f[j & 1][1][i], f[j & 1][2][i], f[j & 1][3][i]);
  }
  __syncthreads();

  // Phase B (unchanged): row d = 64 u16 = 128 B fp4; gsw = (d>>4)&3.
#pragma unroll
  for (int j2 = 0; j2 < 2; ++j2) {
    const int d   = (tid >> 3) + j2 * 32;
    const int o8  = tid & 7;
    const int gsw = (d >> 4) & 3;
    const int g1  = (2 * o8)     ^ gsw;
    const int g2  = (2 * o8 + 1) ^ gsw;
    uint2 a = *(const uint2*)&ls[d * 68 + g1 * 4];
    uint2 b = *(const uint2*)&ls[d * 68 + g2 * 4];
    uint4 v = {a.x, a.y, b.x, b.y};
    *(uint4*)(dst + (size_t)(d0 + d) * (BATCH / 2) + (b0 >> 1) + o8 * 16) = v;
  }
}

// ---------------------------------------------------------------------------
// Kernel 2: Gram tiles, MX-fp4, symmetric (lower-triangle only) with a
// perfectly balanced persistent schedule. Work item q in [0, 8704):
// tile t = q>>5 (t<136: X tile, else Y tile; lower-tri index -> (ti,tj)),
// k-iter = q&31. Block b owns q in [17b, 17b+17) -> every block does
// exactly 17 k-iters, touches <=2 tiles, flushes its accumulator by
// atomicAdd into compact Gc[t] (zeroed by tcvt). Inner loop / swizzle /
// fragment geometry identical to the round-8 proven kernel.
// ---------------------------------------------------------------------------
__global__ __launch_bounds__(256, 2) void gram_fp4(
    const u8* __restrict__ X, const u8* __restrict__ Y,
    float* __restrict__ Gc)
{
  __shared__ u8 ls[2][2][16384];   // [buf][panel I/J][128 rows x 128 B]

  const int tid = threadIdx.x;
  const int bid = blockIdx.x;

  const int wave = tid >> 6;
  const int lane = tid & 63;
  const int wr = (wave >> 1) * 64;
  const int wc = (wave & 1) * 64;
  const int lr = lane & 31;
  const int kh = lane >> 5;          // 16B chunk half within a 32B k-step

  // Staging geometry (block-constant): 16 KB/panel = 4 rounds x 256 x 16 B.
  u32 sdst[4]; int srow[4], sgc16[4];
#pragma unroll
  for (int rr = 0; rr < 4; ++rr) {
    const int li  = rr * 256 + tid;
    const int row = li >> 3;          // 8 chunks of 16B per 128B row
    const int p   = li & 7;
    sdst[rr]  = (u32)(row * 128 + p * 16);
    srow[rr]  = row;
    sgc16[rr] = (p ^ (row & 7)) * 16;
  }

  // Fragment LDS byte addresses: [half][ks 0..3], one b128 each.
  u32 fa[2][4], fb[2][4];
#pragma unroll
  for (int h = 0; h < 2; ++h) {
    const int ra = wr + h * 32 + lr;
    const int rb = wc + h * 32 + lr;
#pragma unroll
    for (int ks = 0; ks < 4; ++ks) {
      const int c = 2 * ks + kh;      // logical 16B chunk 0..7
      fa[h][ks] = (u32)(ra * 128 + (c ^ (ra & 7)) * 16);
      fb[h][ks] = (u32)(rb * 128 + (c ^ (rb & 7)) * 16);
    }
  }

  v16f acc[2][2] = {};
  const int sc = 0x7F7F7F7F;          // e8m0 = 127 -> scale 1.0

  const int q0 = bid * QPB;
  int cur_t = -1, buf = 0;
  const u8* src = X;
  u32 soi[4], soj[4];

  for (int it = 0; it < QPB; ++it) {
    const int q = q0 + it;
    const int t = q >> 5;
    const int k = q & 31;

    if (t != cur_t) {                 // tile setup (uniform across block)
      if (cur_t >= 0) {
        // flush accumulator of previous tile (registers only, no LDS)
        float* gt = Gc + (size_t)cur_t * 16384;
#pragma unroll
        for (int h = 0; h < 2; ++h)
#pragma unroll
          for (int hc = 0; hc < 2; ++hc)
#pragma unroll
            for (int r4 = 0; r4 < 4; ++r4) {
              const int o = (((h * 2 + hc) * 4 + r4) * 256 + tid) * 4;
#pragma unroll
              for (int c2 = 0; c2 < 4; ++c2)
                atomicAdd(gt + o + c2, acc[h][hc][r4 * 4 + c2]);
            }
#pragma unroll
        for (int h = 0; h < 2; ++h)
#pragma unroll
          for (int hc = 0; hc < 2; ++hc)
#pragma unroll
            for (int c2 = 0; c2 < 16; ++c2)
              acc[h][hc][c2] = 0.0f;
      }
      const int ltile = (t < 136) ? t : t - 136;
      src = (t < 136) ? X : Y;
      int ti = 0;
      while ((ti + 1) * (ti + 2) / 2 <= ltile) ++ti;   // lower-tri decode
      const int tj = ltile - ti * (ti + 1) / 2;
      const int i0 = ti * 128;
      const int j0 = tj * 128;
#pragma unroll
      for (int rr = 0; rr < 4; ++rr) {
        soi[rr] = (u32)(i0 + srow[rr]) * (BATCH / 2) + sgc16[rr];
        soj[rr] = (u32)(j0 + srow[rr]) * (BATCH / 2) + sgc16[rr];
      }
      // prologue: stage k-iter k of the new tile into buf
      const u32 kb = (u32)k * 128;    // 128 B fp4 = 256 k per iter
#pragma unroll
      for (int rr = 0; rr < 4; ++rr) {
        gl_lds16(src + soi[rr] + kb, &ls[buf][0][sdst[rr]]);
        gl_lds16(src + soj[rr] + kb, &ls[buf][1][sdst[rr]]);
      }
      cur_t = t;
    }

    __syncthreads();                  // staging of buf done; buf^1 free
    if (it + 1 < QPB && ((q + 1) >> 5) == t) {
      const u32 kb = (u32)(k + 1) * 128;
#pragma unroll
      for (int rr = 0; rr < 4; ++rr) {
        gl_lds16(src + soi[rr] + kb, &ls[buf ^ 1][0][sdst[rr]]);
        gl_lds16(src + soj[rr] + kb, &ls[buf ^ 1][1][sdst[rr]]);
      }
    }

    const u8* pI = ls[buf][0];
    const u8* pJ = ls[buf][1];
#pragma unroll
    for (int ks = 0; ks < 4; ++ks) {
      v8i a[2], b[2];
#pragma unroll
      for (int h = 0; h < 2; ++h) {
        int4 pa = *(const int4*)&pI[fa[h][ks]];
        a[h] = (v8i){pa.x, pa.y, pa.z, pa.w, 0, 0, 0, 0};
        int4 pb = *(const int4*)&pJ[fb[h][ks]];
        b[h] = (v8i){pb.x, pb.y, pb.z, pb.w, 0, 0, 0, 0};
      }
#pragma unroll
      for (int h = 0; h < 2; ++h)
#pragma unroll
        for (int hc = 0; hc < 2; ++hc)
          acc[h][hc] = __builtin_amdgcn_mfma_scale_f32_32x32x64_f8f6f4(
              a[h], b[hc], acc[h][hc], /*cbsz=fp4*/ 4, /*blgp=fp4*/ 4,
              0, sc, 0, sc);
    }
    buf ^= 1;
  }

  // final flush (lane-slot order: identical permutation for X/Y tile lt ->
  // elementwise dot invariant)
  {
    float* gt = Gc + (size_t)cur_t * 16384;
#pragma unroll
    for (int h = 0; h < 2; ++h)
#pragma unroll
      for (int hc = 0; hc < 2; ++hc)
#pragma unroll
        for (int r4 = 0; r4 < 4; ++r4) {
          const int o = (((h * 2 + hc) * 4 + r4) * 256 + tid) * 4;
#pragma unroll
          for (int c2 = 0; c2 < 4; ++c2)
            atomicAdd(gt + o + c2, acc[h][hc][r4 * 4 + c2]);
        }
  }
}

// ---------------------------------------------------------------------------
// Kernel 3: weighted elementwise dot over the 136 lower-tri tile pairs
// (weight 2 off-diagonal, 1 diagonal) + fused finalize (ticket).
// Grid = 136 tiles x 2 halves = 272 blocks.
// ---------------------------------------------------------------------------
__global__ __launch_bounds__(256) void dot_kernel(
    const float4* __restrict__ Gc4,
    float* __restrict__ d_acc, u32* __restrict__ d_cnt,
    float* __restrict__ out)
{
  __shared__ float red[4];
  const int tid  = threadIdx.x;
  const int lane = tid & 63;
  const int lt   = blockIdx.x >> 1;
  const int half = blockIdx.x & 1;

  int ti = 0;
  while ((ti + 1) * (ti + 2) / 2 <= lt) ++ti;
  const int tj = lt - ti * (ti + 1) / 2;
  const float w = (ti == tj) ? 1.0f : 2.0f;

  const float4* gx = Gc4 + (size_t)lt * 4096 + half * 2048;          // X tile
  const float4* gy = Gc4 + (size_t)(136 + lt) * 4096 + half * 2048;  // Y tile
  float s = 0.0f;
#pragma unroll
  for (int j = 0; j < 8; ++j) {
    float4 a = gx[tid + j * 256];
    float4 b = gy[tid + j * 256];
    s += a.x * b.x + a.y * b.y + a.z * b.z + a.w * b.w;
  }
  s *= w;
#pragma unroll
  for (int off = 32; off > 0; off >>= 1)
    s += __shfl_down(s, off);
  if (lane == 0) red[tid >> 6] = s;
  __syncthreads();
  if (tid == 0) {
    atomicAdd(d_acc, red[0] + red[1] + red[2] + red[3]);
    __threadfence();
    const u32 old = atomicAdd(d_cnt, 1u);
    if (old == 271u) {                     // last of 272 blocks
      float S   = atomicAdd(d_acc, 0.0f);  // device-coherent read
      // fidelity = S / (B^2 * 64^4) = S * 2^-50
      float fid = S * 0x1.0p-50f;
      fid = fminf(fmaxf(fid, 0.0f), 1.0f);
      *out = 0.1f * fabsf(fid - 0.95f);
    }
  }
}

extern "C" void kernel_launch(void* const* d_in, const int* in_sizes, int n_in,
                              void* d_out, int out_size, void* d_ws, size_t ws_size,
                              hipStream_t stream) {
  const float* L = (const float*)d_in[0];
  const float* T = (const float*)d_in[1];
  float* out = (float*)d_out;

  const size_t NF4 = (size_t)BATCH * DIM / 2;    // 8,388,608 B per fp4 tensor
  u8*    X   = (u8*)d_ws;
  u8*    Y   = (u8*)d_ws + NF4;
  float* Gc  = (float*)((char*)d_ws + 2 * NF4);  // compact: [272 tiles][16384 f]
  float* acc = Gc + (size_t)NT * 16384;
  u32*   cnt = (u32*)(acc + 1);

  tcvt_fp4<<<2048, 256, 0, stream>>>(L, T, X, Y, Gc, acc, cnt);
  gram_fp4<<<512, 256, 0, stream>>>(X, Y, Gc);
  dot_kernel<<<272, 256, 0, stream>>>((const float4*)Gc, acc, cnt, out);
}

// Round 2
// 199.870 us; speedup vs baseline: 1.6215x; 1.6215x over previous
//
#include <hip/hip_runtime.h>
#include <stdint.h>

#define BATCH 8192   // Gram K dimension
#define DIM   2048   // Gram M and N
#define NT    272    // symmetric tiles: 136 per Gram x 2 Grams
#define QTOT  (NT * 32)        // 8704 (tile, k-iter) work items
#define QPB   17               // 8704 / 512 blocks, exact
#define NSLOT 768              // total (block, tile) piece slots

typedef unsigned char  u8;
typedef unsigned short u16;
typedef unsigned int   u32;

using v8i   = __attribute__((ext_vector_type(8)))  int;
using v16f  = __attribute__((ext_vector_type(16))) float;
using f32x4 = __attribute__((ext_vector_type(4)))  float;

#if __has_builtin(__builtin_amdgcn_cvt_scalef32_pk_fp4_f32)
#define HW_FP4 1
#endif

// async global->LDS, 16B per lane; dest must be wave-uniform base + lane*16.
__device__ __forceinline__ void gl_lds16(const void* g, void* l) {
  __builtin_amdgcn_global_load_lds(
      (const __attribute__((address_space(1))) u32*)g,
      (__attribute__((address_space(3))) u32*)l, 16, 0, 0);
}

// Piece-slot compaction. Block b is a "straddler" (covers 2 tiles) iff
// (17*b mod 32) >= 16. Straddlers before b, closed form over the period-32
// residue pattern: r even & r>=16, or r odd & r<16.
__device__ __forceinline__ int piece_base(int b) {
  const int m = b & 31;
  const int p = (m <= 16) ? (m >> 1) : (8 + ((m - 15) >> 1));
  return b + 16 * (b >> 5) + p;
}

// Fallback f32 -> fp4 e2m1 nibble of (64*x), round-to-nearest.
__device__ __forceinline__ u32 nib4(float x) {
  float xs = x * 64.0f;
  float a  = fabsf(xs);
  u32 n = (u32)(a >= 0.25f) + (u32)(a >= 0.75f) + (u32)(a >= 1.25f) +
          (u32)(a >= 1.75f) + (u32)(a >= 2.5f)  + (u32)(a >= 3.5f)  +
          (u32)(a >= 5.0f);
  return n | (xs < 0.0f ? 8u : 0u);
}

// Pack 4 floats (quant domain = 64*x) into 4 e2m1 nibbles (u16).
__device__ __forceinline__ u16 pack4_fp4(float a, float b, float c, float d) {
#ifdef HW_FP4
  u32 w = __builtin_amdgcn_cvt_scalef32_pk_fp4_f32(0u,  a * 64.0f, b * 64.0f, 1.0f, 0);
  w     = __builtin_amdgcn_cvt_scalef32_pk_fp4_f32(w,   c * 64.0f, d * 64.0f, 1.0f, 1);
  return (u16)w;   // nibble-order differences are k-permutations -> cancel
#else
  return (u16)(nib4(a) | (nib4(b) << 4) | (nib4(c) << 8) | (nib4(d) << 12));
#endif
}

// ---------------------------------------------------------------------------
// Kernel 1: fused transpose + f32->fp4. src [8192 b][2048 d] f32 ->
// dst [2048 d][8192 b-fp4] (4096 B/row). Round-9 register pipeline kept
// (ext_vector + constant subscripts only); round-10: Gc zero-init removed
// (gram now writes private piece slots, fully overwritten).
// ---------------------------------------------------------------------------
__global__ __launch_bounds__(256) void tcvt_fp4(
    const float* __restrict__ L, const float* __restrict__ T,
    u8* __restrict__ X, u8* __restrict__ Y,
    float* __restrict__ acc, u32* __restrict__ cnt)
{
  __shared__ u16 ls[64 * 68];   // [d][64 u16 payload + 4 pad]

  const int tid = threadIdx.x;
  if (blockIdx.x == 0 && tid == 0) { *acc = 0.0f; *cnt = 0u; }

  int id = blockIdx.x;
  const float* src;
  u8* dst;
  if (id < 1024) { src = L; dst = X; }
  else           { src = T; dst = Y; id -= 1024; }
  const int d0 = (id & 31) * 64;
  const int b0 = (id >> 5) * 256;

  const int s  = tid & 15;          // d-slot (d = 4s..4s+3)
  const int g  = tid >> 4;          // b row-group
  const int sw = s & 12;

  const float* base = src + (size_t)(b0 + g * 4) * DIM + d0 + s * 4;

  // 2-deep pipeline: load j-group j+1 while packing j-group j.
  f32x4 f[2][4];
#pragma unroll
  for (int r = 0; r < 4; ++r)
    f[0][r] = *(const f32x4*)(base + (size_t)r * DIM);

#pragma unroll
  for (int j = 0; j < 4; ++j) {
    if (j < 3) {
#pragma unroll
      for (int r = 0; r < 4; ++r)
        f[(j + 1) & 1][r] = *(const f32x4*)(base + (size_t)((j + 1) * 64 + r) * DIM);
    }
    const int w = (j * 16 + g) ^ sw;   // u16 column 0..63
#pragma unroll
    for (int i = 0; i < 4; ++i)
      ls[(s * 4 + i) * 68 + w] =
          pack4_fp4(f[j & 1][0][i], f[j & 1][1][i], f[j & 1][2][i], f[j & 1][3][i]);
  }
  __syncthreads();

  // Phase B (unchanged): row d = 64 u16 = 128 B fp4; gsw = (d>>4)&3.
#pragma unroll
  for (int j2 = 0; j2 < 2; ++j2) {
    const int d   = (tid >> 3) + j2 * 32;
    const int o8  = tid & 7;
    const int gsw = (d >> 4) & 3;
    const int g1  = (2 * o8)     ^ gsw;
    const int g2  = (2 * o8 + 1) ^ gsw;
    uint2 a = *(const uint2*)&ls[d * 68 + g1 * 4];
    uint2 b = *(const uint2*)&ls[d * 68 + g2 * 4];
    uint4 v = {a.x, a.y, b.x, b.y};
    *(uint4*)(dst + (size_t)(d0 + d) * (BATCH / 2) + (b0 >> 1) + o8 * 16) = v;
  }
}

// ---------------------------------------------------------------------------
// Kernel 2: Gram tiles, MX-fp4, symmetric lower-triangle, balanced
// persistent schedule (512 blocks x exactly 17 k-iters). Round-10 fix:
// the round-9 atomicAdd flush (CAS loop -> 64 dependent round-trips per
// thread, ~165 us tail, WRITE_SIZE 196 MB) is replaced by plain float4
// stores into a private piece slot per (block, tile); dot sums pieces.
// Flush stores are issued after the new tile's async staging so the
// switch latency hides under them. MFMA loop / swizzle unchanged (proven).
// ---------------------------------------------------------------------------
__global__ __launch_bounds__(256, 2) void gram_fp4(
    const u8* __restrict__ X, const u8* __restrict__ Y,
    float* __restrict__ P)
{
  __shared__ u8 ls[2][2][16384];   // [buf][panel I/J][128 rows x 128 B]

  const int tid = threadIdx.x;
  const int bid = blockIdx.x;

  const int wave = tid >> 6;
  const int lane = tid & 63;
  const int wr = (wave >> 1) * 64;
  const int wc = (wave & 1) * 64;
  const int lr = lane & 31;
  const int kh = lane >> 5;          // 16B chunk half within a 32B k-step

  // Staging geometry (block-constant): 16 KB/panel = 4 rounds x 256 x 16 B.
  u32 sdst[4]; int srow[4], sgc16[4];
#pragma unroll
  for (int rr = 0; rr < 4; ++rr) {
    const int li  = rr * 256 + tid;
    const int row = li >> 3;          // 8 chunks of 16B per 128B row
    const int p   = li & 7;
    sdst[rr]  = (u32)(row * 128 + p * 16);
    srow[rr]  = row;
    sgc16[rr] = (p ^ (row & 7)) * 16;
  }

  // Fragment LDS byte addresses: [half][ks 0..3], one b128 each.
  u32 fa[2][4], fb[2][4];
#pragma unroll
  for (int h = 0; h < 2; ++h) {
    const int ra = wr + h * 32 + lr;
    const int rb = wc + h * 32 + lr;
#pragma unroll
    for (int ks = 0; ks < 4; ++ks) {
      const int c = 2 * ks + kh;      // logical 16B chunk 0..7
      fa[h][ks] = (u32)(ra * 128 + (c ^ (ra & 7)) * 16);
      fb[h][ks] = (u32)(rb * 128 + (c ^ (rb & 7)) * 16);
    }
  }

  v16f acc[2][2] = {};
  const int sc = 0x7F7F7F7F;          // e8m0 = 127 -> scale 1.0

  const int q0  = bid * QPB;
  const int t0b = q0 >> 5;            // block's first tile
  const int sl0 = piece_base(bid);    // block's first piece slot
  int cur_t = -1, buf = 0;
  const u8* src = X;
  u32 soi[4], soj[4];

  for (int it = 0; it < QPB; ++it) {
    const int q = q0 + it;
    const int t = q >> 5;
    const int k = q & 31;

    if (t != cur_t) {                 // tile switch (uniform across block)
      // (a) set up + issue async staging of the NEW tile first
      const int ltile = (t < 136) ? t : t - 136;
      src = (t < 136) ? X : Y;
      int ti = 0;
      while ((ti + 1) * (ti + 2) / 2 <= ltile) ++ti;   // lower-tri decode
      const int tj = ltile - ti * (ti + 1) / 2;
      const int i0 = ti * 128;
      const int j0 = tj * 128;
#pragma unroll
      for (int rr = 0; rr < 4; ++rr) {
        soi[rr] = (u32)(i0 + srow[rr]) * (BATCH / 2) + sgc16[rr];
        soj[rr] = (u32)(j0 + srow[rr]) * (BATCH / 2) + sgc16[rr];
      }
      const u32 kb = (u32)k * 128;    // 128 B fp4 = 256 k per iter
#pragma unroll
      for (int rr = 0; rr < 4; ++rr) {
        gl_lds16(src + soi[rr] + kb, &ls[buf][0][sdst[rr]]);
        gl_lds16(src + soj[rr] + kb, &ls[buf][1][sdst[rr]]);
      }
      // (b) flush previous tile's accumulator: plain float4 stores into the
      //     private piece slot (hides under the staging just issued).
      if (cur_t >= 0) {
        float4* o = (float4*)(P + (size_t)(sl0 + (cur_t - t0b)) * 16384);
#pragma unroll
        for (int h = 0; h < 2; ++h)
#pragma unroll
          for (int hc = 0; hc < 2; ++hc)
#pragma unroll
            for (int r4 = 0; r4 < 4; ++r4) {
              float4 v = {acc[h][hc][r4 * 4 + 0], acc[h][hc][r4 * 4 + 1],
                          acc[h][hc][r4 * 4 + 2], acc[h][hc][r4 * 4 + 3]};
              o[((h * 2 + hc) * 4 + r4) * 256 + tid] = v;
            }
#pragma unroll
        for (int h = 0; h < 2; ++h)
#pragma unroll
          for (int hc = 0; hc < 2; ++hc)
#pragma unroll
            for (int c2 = 0; c2 < 16; ++c2)
              acc[h][hc][c2] = 0.0f;
      }
      cur_t = t;
    }

    __syncthreads();                  // staging of buf done; buf^1 free
    if (it + 1 < QPB && ((q + 1) >> 5) == t) {
      const u32 kb = (u32)(k + 1) * 128;
#pragma unroll
      for (int rr = 0; rr < 4; ++rr) {
        gl_lds16(src + soi[rr] + kb, &ls[buf ^ 1][0][sdst[rr]]);
        gl_lds16(src + soj[rr] + kb, &ls[buf ^ 1][1][sdst[rr]]);
      }
    }

    const u8* pI = ls[buf][0];
    const u8* pJ = ls[buf][1];
#pragma unroll
    for (int ks = 0; ks < 4; ++ks) {
      v8i a[2], b[2];
#pragma unroll
      for (int h = 0; h < 2; ++h) {
        int4 pa = *(const int4*)&pI[fa[h][ks]];
        a[h] = (v8i){pa.x, pa.y, pa.z, pa.w, 0, 0, 0, 0};
        int4 pb = *(const int4*)&pJ[fb[h][ks]];
        b[h] = (v8i){pb.x, pb.y, pb.z, pb.w, 0, 0, 0, 0};
      }
#pragma unroll
      for (int h = 0; h < 2; ++h)
#pragma unroll
        for (int hc = 0; hc < 2; ++hc)
          acc[h][hc] = __builtin_amdgcn_mfma_scale_f32_32x32x64_f8f6f4(
              a[h], b[hc], acc[h][hc], /*cbsz=fp4*/ 4, /*blgp=fp4*/ 4,
              0, sc, 0, sc);
    }
    buf ^= 1;
  }

  // final flush (same lane-slot order: permutation cancels in the dot)
  {
    float4* o = (float4*)(P + (size_t)(sl0 + (cur_t - t0b)) * 16384);
#pragma unroll
    for (int h = 0; h < 2; ++h)
#pragma unroll
      for (int hc = 0; hc < 2; ++hc)
#pragma unroll
        for (int r4 = 0; r4 < 4; ++r4) {
          float4 v = {acc[h][hc][r4 * 4 + 0], acc[h][hc][r4 * 4 + 1],
                      acc[h][hc][r4 * 4 + 2], acc[h][hc][r4 * 4 + 3]};
          o[((h * 2 + hc) * 4 + r4) * 256 + tid] = v;
        }
  }
}

// ---------------------------------------------------------------------------
// Kernel 3: weighted dot over 136 lower-tri tile pairs. Each tile's Gram
// value = sum of its 2-3 pieces (summed elementwise before the product;
// identical slot order across pieces -> permutation cancels).
// Grid = 136 tiles x 2 halves = 272 blocks. Fused finalize via ticket.
// ---------------------------------------------------------------------------
__device__ __forceinline__ int collect_pieces(int t, int* s) {
  const int qlo = 32 * t, qhi = 32 * t + 31;
  const int b_lo = qlo / 17, b_hi = qhi / 17;
  int n = 0;
  for (int b = b_lo; b <= b_hi; ++b) {
    const int tfirst = (17 * b) >> 5;
    s[n++] = piece_base(b) + (t - tfirst);
  }
  return n;   // 2 or 3
}

__global__ __launch_bounds__(256) void dot_kernel(
    const float4* __restrict__ P4,
    float* __restrict__ d_acc, u32* __restrict__ d_cnt,
    float* __restrict__ out)
{
  __shared__ float red[4];
  const int tid  = threadIdx.x;
  const int lane = tid & 63;
  const int lt   = blockIdx.x >> 1;
  const int half = blockIdx.x & 1;

  int ti = 0;
  while ((ti + 1) * (ti + 2) / 2 <= lt) ++ti;
  const int tj = lt - ti * (ti + 1) / 2;
  const float w = (ti == tj) ? 1.0f : 2.0f;

  int sx[3], sy[3];
  const int nx = collect_pieces(lt, sx);
  const int ny = collect_pieces(136 + lt, sy);

  const size_t ho = (size_t)half * 2048;
  float s = 0.0f;
#pragma unroll
  for (int j = 0; j < 8; ++j) {
    const int e = tid + j * 256;
    float4 a = P4[(size_t)sx[0] * 4096 + ho + e];
    {
      float4 u = P4[(size_t)sx[1] * 4096 + ho + e];
      a.x += u.x; a.y += u.y; a.z += u.z; a.w += u.w;
    }
    if (nx == 3) {
      float4 u = P4[(size_t)sx[2] * 4096 + ho + e];
      a.x += u.x; a.y += u.y; a.z += u.z; a.w += u.w;
    }
    float4 b = P4[(size_t)sy[0] * 4096 + ho + e];
    {
      float4 u = P4[(size_t)sy[1] * 4096 + ho + e];
      b.x += u.x; b.y += u.y; b.z += u.z; b.w += u.w;
    }
    if (ny == 3) {
      float4 u = P4[(size_t)sy[2] * 4096 + ho + e];
      b.x += u.x; b.y += u.y; b.z += u.z; b.w += u.w;
    }
    s += a.x * b.x + a.y * b.y + a.z * b.z + a.w * b.w;
  }
  s *= w;
#pragma unroll
  for (int off = 32; off > 0; off >>= 1)
    s += __shfl_down(s, off);
  if (lane == 0) red[tid >> 6] = s;
  __syncthreads();
  if (tid == 0) {
    atomicAdd(d_acc, red[0] + red[1] + red[2] + red[3]);
    __threadfence();
    const u32 old = atomicAdd(d_cnt, 1u);
    if (old == 271u) {                     // last of 272 blocks
      float S   = atomicAdd(d_acc, 0.0f);  // device-coherent read
      // fidelity = S / (B^2 * 64^4) = S * 2^-50
      float fid = S * 0x1.0p-50f;
      fid = fminf(fmaxf(fid, 0.0f), 1.0f);
      *out = 0.1f * fabsf(fid - 0.95f);
    }
  }
}

extern "C" void kernel_launch(void* const* d_in, const int* in_sizes, int n_in,
                              void* d_out, int out_size, void* d_ws, size_t ws_size,
                              hipStream_t stream) {
  const float* L = (const float*)d_in[0];
  const float* T = (const float*)d_in[1];
  float* out = (float*)d_out;

  const size_t NF4 = (size_t)BATCH * DIM / 2;    // 8,388,608 B per fp4 tensor
  u8*    X   = (u8*)d_ws;
  u8*    Y   = (u8*)d_ws + NF4;
  float* P   = (float*)((char*)d_ws + 2 * NF4);  // 768 piece slots x 64 KB
  float* acc = P + (size_t)NSLOT * 16384;
  u32*   cnt = (u32*)(acc + 1);

  tcvt_fp4<<<2048, 256, 0, stream>>>(L, T, X, Y, acc, cnt);
  gram_fp4<<<512, 256, 0, stream>>>(X, Y, P);
  dot_kernel<<<272, 256, 0, stream>>>((const float4*)P, acc, cnt, out);
}

// Round 3
// 198.076 us; speedup vs baseline: 1.6362x; 1.0091x over previous
//
#include <hip/hip_runtime.h>
#include <stdint.h>

#define BATCH 8192   // Gram K dimension
#define DIM   2048   // Gram M and N
#define NT    272    // symmetric tiles: 136 per Gram x 2 Grams
#define QTOT  (NT * 32)        // 8704 (tile, k-iter) work items
#define QPB   17               // 8704 / 512 blocks, exact
#define NSLOT 768              // total (block, tile) piece slots

typedef unsigned char  u8;
typedef unsigned short u16;
typedef unsigned int   u32;

using v8i   = __attribute__((ext_vector_type(8)))  int;
using v16f  = __attribute__((ext_vector_type(16))) float;
using f32x4 = __attribute__((ext_vector_type(4)))  float;

#if __has_builtin(__builtin_amdgcn_cvt_scalef32_pk_fp4_f32)
#define HW_FP4 1
#endif

// async global->LDS, 16B per lane; dest must be wave-uniform base + lane*16.
__device__ __forceinline__ void gl_lds16(const void* g, void* l) {
  __builtin_amdgcn_global_load_lds(
      (const __attribute__((address_space(1))) u32*)g,
      (__attribute__((address_space(3))) u32*)l, 16, 0, 0);
}

// Piece-slot compaction. Block b is a "straddler" (covers 2 tiles) iff
// (17*b mod 32) >= 16. Straddlers before b, closed form over the period-32
// residue pattern.
__device__ __forceinline__ int piece_base(int b) {
  const int m = b & 31;
  const int p = (m <= 16) ? (m >> 1) : (8 + ((m - 15) >> 1));
  return b + 16 * (b >> 5) + p;
}

// Fallback f32 -> fp4 e2m1 nibble of (64*x), round-to-nearest.
__device__ __forceinline__ u32 nib4(float x) {
  float xs = x * 64.0f;
  float a  = fabsf(xs);
  u32 n = (u32)(a >= 0.25f) + (u32)(a >= 0.75f) + (u32)(a >= 1.25f) +
          (u32)(a >= 1.75f) + (u32)(a >= 2.5f)  + (u32)(a >= 3.5f)  +
          (u32)(a >= 5.0f);
  return n | (xs < 0.0f ? 8u : 0u);
}

// Pack 4 floats (quant domain = 64*x) into 4 e2m1 nibbles (u16).
__device__ __forceinline__ u16 pack4_fp4(float a, float b, float c, float d) {
#ifdef HW_FP4
  u32 w = __builtin_amdgcn_cvt_scalef32_pk_fp4_f32(0u,  a * 64.0f, b * 64.0f, 1.0f, 0);
  w     = __builtin_amdgcn_cvt_scalef32_pk_fp4_f32(w,   c * 64.0f, d * 64.0f, 1.0f, 1);
  return (u16)w;   // nibble-order differences are k-permutations -> cancel
#else
  return (u16)(nib4(a) | (nib4(b) << 4) | (nib4(c) << 8) | (nib4(d) << 12));
#endif
}

// ---------------------------------------------------------------------------
// Kernel 1: fused transpose + f32->fp4. src [8192 b][2048 d] f32 ->
// dst [2048 d][8192 b-fp4] (4096 B/row).
// Round-11: rounds 8/9 both failed to hoist loads (VGPR_Count 32/28 proves
// the backend re-sank them; latency-bound at 4 dependent round trips).
// Now: 16 NAMED f32x4 loads + sched_barrier(0) — a hard scheduling-region
// fence the backend cannot sink loads across. One vmcnt ramp, 16 loads in
// flight per wave.
// ---------------------------------------------------------------------------
__global__ __launch_bounds__(256) void tcvt_fp4(
    const float* __restrict__ L, const float* __restrict__ T,
    u8* __restrict__ X, u8* __restrict__ Y,
    float* __restrict__ acc, u32* __restrict__ cnt)
{
  __shared__ u16 ls[64 * 68];   // [d][64 u16 payload + 4 pad]

  const int tid = threadIdx.x;
  if (blockIdx.x == 0 && tid == 0) { *acc = 0.0f; *cnt = 0u; }

  int id = blockIdx.x;
  const float* src;
  u8* dst;
  if (id < 1024) { src = L; dst = X; }
  else           { src = T; dst = Y; id -= 1024; }
  const int d0 = (id & 31) * 64;
  const int b0 = (id >> 5) * 256;

  const int s  = tid & 15;          // d-slot (d = 4s..4s+3)
  const int g  = tid >> 4;          // b row-group
  const int sw = s & 12;

  const float* base = src + (size_t)(b0 + g * 4) * DIM + d0 + s * 4;

#define LDJR(j, r) (*(const f32x4*)(base + (size_t)((j) * 64 + (r)) * DIM))
  f32x4 f00 = LDJR(0, 0), f01 = LDJR(0, 1), f02 = LDJR(0, 2), f03 = LDJR(0, 3);
  f32x4 f10 = LDJR(1, 0), f11 = LDJR(1, 1), f12 = LDJR(1, 2), f13 = LDJR(1, 3);
  f32x4 f20 = LDJR(2, 0), f21 = LDJR(2, 1), f22 = LDJR(2, 2), f23 = LDJR(2, 3);
  f32x4 f30 = LDJR(3, 0), f31 = LDJR(3, 1), f32_ = LDJR(3, 2), f33 = LDJR(3, 3);
#undef LDJR
  __builtin_amdgcn_sched_barrier(0);   // loads may NOT sink past this point

#define PACKJ(j, a, b, c, d)                                                \
  {                                                                         \
    const int w = ((j) * 16 + g) ^ sw;                                      \
    ls[(s * 4 + 0) * 68 + w] = pack4_fp4((a)[0], (b)[0], (c)[0], (d)[0]);   \
    ls[(s * 4 + 1) * 68 + w] = pack4_fp4((a)[1], (b)[1], (c)[1], (d)[1]);   \
    ls[(s * 4 + 2) * 68 + w] = pack4_fp4((a)[2], (b)[2], (c)[2], (d)[2]);   \
    ls[(s * 4 + 3) * 68 + w] = pack4_fp4((a)[3], (b)[3], (c)[3], (d)[3]);   \
  }
  PACKJ(0, f00, f01, f02, f03)
  PACKJ(1, f10, f11, f12, f13)
  PACKJ(2, f20, f21, f22, f23)
  PACKJ(3, f30, f31, f32_, f33)
#undef PACKJ
  __syncthreads();

  // Phase B (unchanged): row d = 64 u16 = 128 B fp4; gsw = (d>>4)&3.
#pragma unroll
  for (int j2 = 0; j2 < 2; ++j2) {
    const int d   = (tid >> 3) + j2 * 32;
    const int o8  = tid & 7;
    const int gsw = (d >> 4) & 3;
    const int g1  = (2 * o8)     ^ gsw;
    const int g2  = (2 * o8 + 1) ^ gsw;
    uint2 a = *(const uint2*)&ls[d * 68 + g1 * 4];
    uint2 b = *(const uint2*)&ls[d * 68 + g2 * 4];
    uint4 v = {a.x, a.y, b.x, b.y};
    *(uint4*)(dst + (size_t)(d0 + d) * (BATCH / 2) + (b0 >> 1) + o8 * 16) = v;
  }
}

// ---------------------------------------------------------------------------
// Kernel 2: Gram tiles, MX-fp4, symmetric lower-triangle, balanced
// persistent schedule (512 blocks x exactly 17 k-iters), private piece-slot
// flush (proven round-10). Round-11 micro: diagonal tiles (i0==j0, 32 of
// 272) skip panel-J staging entirely and alias pJ -> panel I (identical
// data, ~6% less staging). MFMA loop / swizzle unchanged (proven).
// ---------------------------------------------------------------------------
__global__ __launch_bounds__(256, 2) void gram_fp4(
    const u8* __restrict__ X, const u8* __restrict__ Y,
    float* __restrict__ P)
{
  __shared__ u8 ls[2][2][16384];   // [buf][panel I/J][128 rows x 128 B]

  const int tid = threadIdx.x;
  const int bid = blockIdx.x;

  const int wave = tid >> 6;
  const int lane = tid & 63;
  const int wr = (wave >> 1) * 64;
  const int wc = (wave & 1) * 64;
  const int lr = lane & 31;
  const int kh = lane >> 5;          // 16B chunk half within a 32B k-step

  // Staging geometry (block-constant): 16 KB/panel = 4 rounds x 256 x 16 B.
  u32 sdst[4]; int srow[4], sgc16[4];
#pragma unroll
  for (int rr = 0; rr < 4; ++rr) {
    const int li  = rr * 256 + tid;
    const int row = li >> 3;          // 8 chunks of 16B per 128B row
    const int p   = li & 7;
    sdst[rr]  = (u32)(row * 128 + p * 16);
    srow[rr]  = row;
    sgc16[rr] = (p ^ (row & 7)) * 16;
  }

  // Fragment LDS byte addresses: [half][ks 0..3], one b128 each.
  u32 fa[2][4], fb[2][4];
#pragma unroll
  for (int h = 0; h < 2; ++h) {
    const int ra = wr + h * 32 + lr;
    const int rb = wc + h * 32 + lr;
#pragma unroll
    for (int ks = 0; ks < 4; ++ks) {
      const int c = 2 * ks + kh;      // logical 16B chunk 0..7
      fa[h][ks] = (u32)(ra * 128 + (c ^ (ra & 7)) * 16);
      fb[h][ks] = (u32)(rb * 128 + (c ^ (rb & 7)) * 16);
    }
  }

  v16f acc[2][2] = {};
  const int sc = 0x7F7F7F7F;          // e8m0 = 127 -> scale 1.0

  const int q0  = bid * QPB;
  const int t0b = q0 >> 5;            // block's first tile
  const int sl0 = piece_base(bid);    // block's first piece slot
  int cur_t = -1, buf = 0;
  bool diag = false;
  const u8* src = X;
  u32 soi[4], soj[4];

  for (int it = 0; it < QPB; ++it) {
    const int q = q0 + it;
    const int t = q >> 5;
    const int k = q & 31;

    if (t != cur_t) {                 // tile switch (uniform across block)
      // (a) set up + issue async staging of the NEW tile first
      const int ltile = (t < 136) ? t : t - 136;
      src = (t < 136) ? X : Y;
      int ti = 0;
      while ((ti + 1) * (ti + 2) / 2 <= ltile) ++ti;   // lower-tri decode
      const int tj = ltile - ti * (ti + 1) / 2;
      const int i0 = ti * 128;
      const int j0 = tj * 128;
      diag = (ti == tj);
#pragma unroll
      for (int rr = 0; rr < 4; ++rr) {
        soi[rr] = (u32)(i0 + srow[rr]) * (BATCH / 2) + sgc16[rr];
        soj[rr] = (u32)(j0 + srow[rr]) * (BATCH / 2) + sgc16[rr];
      }
      const u32 kb = (u32)k * 128;    // 128 B fp4 = 256 k per iter
#pragma unroll
      for (int rr = 0; rr < 4; ++rr)
        gl_lds16(src + soi[rr] + kb, &ls[buf][0][sdst[rr]]);
      if (!diag)
#pragma unroll
        for (int rr = 0; rr < 4; ++rr)
          gl_lds16(src + soj[rr] + kb, &ls[buf][1][sdst[rr]]);
      // (b) flush previous tile's accumulator: plain float4 stores into the
      //     private piece slot (hides under the staging just issued).
      if (cur_t >= 0) {
        float4* o = (float4*)(P + (size_t)(sl0 + (cur_t - t0b)) * 16384);
#pragma unroll
        for (int h = 0; h < 2; ++h)
#pragma unroll
          for (int hc = 0; hc < 2; ++hc)
#pragma unroll
            for (int r4 = 0; r4 < 4; ++r4) {
              float4 v = {acc[h][hc][r4 * 4 + 0], acc[h][hc][r4 * 4 + 1],
                          acc[h][hc][r4 * 4 + 2], acc[h][hc][r4 * 4 + 3]};
              o[((h * 2 + hc) * 4 + r4) * 256 + tid] = v;
            }
#pragma unroll
        for (int h = 0; h < 2; ++h)
#pragma unroll
          for (int hc = 0; hc < 2; ++hc)
#pragma unroll
            for (int c2 = 0; c2 < 16; ++c2)
              acc[h][hc][c2] = 0.0f;
      }
      cur_t = t;
    }

    __syncthreads();                  // staging of buf done; buf^1 free
    if (it + 1 < QPB && ((q + 1) >> 5) == t) {
      const u32 kb = (u32)(k + 1) * 128;
#pragma unroll
      for (int rr = 0; rr < 4; ++rr)
        gl_lds16(src + soi[rr] + kb, &ls[buf ^ 1][0][sdst[rr]]);
      if (!diag)
#pragma unroll
        for (int rr = 0; rr < 4; ++rr)
          gl_lds16(src + soj[rr] + kb, &ls[buf ^ 1][1][sdst[rr]]);
    }

    const u8* pI = ls[buf][0];
    const u8* pJ = diag ? ls[buf][0] : ls[buf][1];
#pragma unroll
    for (int ks = 0; ks < 4; ++ks) {
      v8i a[2], b[2];
#pragma unroll
      for (int h = 0; h < 2; ++h) {
        int4 pa = *(const int4*)&pI[fa[h][ks]];
        a[h] = (v8i){pa.x, pa.y, pa.z, pa.w, 0, 0, 0, 0};
        int4 pb = *(const int4*)&pJ[fb[h][ks]];
        b[h] = (v8i){pb.x, pb.y, pb.z, pb.w, 0, 0, 0, 0};
      }
#pragma unroll
      for (int h = 0; h < 2; ++h)
#pragma unroll
        for (int hc = 0; hc < 2; ++hc)
          acc[h][hc] = __builtin_amdgcn_mfma_scale_f32_32x32x64_f8f6f4(
              a[h], b[hc], acc[h][hc], /*cbsz=fp4*/ 4, /*blgp=fp4*/ 4,
              0, sc, 0, sc);
    }
    buf ^= 1;
  }

  // final flush (same lane-slot order: permutation cancels in the dot)
  {
    float4* o = (float4*)(P + (size_t)(sl0 + (cur_t - t0b)) * 16384);
#pragma unroll
    for (int h = 0; h < 2; ++h)
#pragma unroll
      for (int hc = 0; hc < 2; ++hc)
#pragma unroll
        for (int r4 = 0; r4 < 4; ++r4) {
          float4 v = {acc[h][hc][r4 * 4 + 0], acc[h][hc][r4 * 4 + 1],
                      acc[h][hc][r4 * 4 + 2], acc[h][hc][r4 * 4 + 3]};
          o[((h * 2 + hc) * 4 + r4) * 256 + tid] = v;
        }
  }
}

// ---------------------------------------------------------------------------
// Kernel 3: weighted dot over 136 lower-tri tile pairs. Each tile's Gram
// value = sum of its 2-3 pieces (summed elementwise before the product;
// identical slot order across pieces -> permutation cancels).
// Grid = 136 tiles x 2 halves = 272 blocks. Fused finalize via ticket.
// ---------------------------------------------------------------------------
__device__ __forceinline__ int collect_pieces(int t, int* s) {
  const int qlo = 32 * t, qhi = 32 * t + 31;
  const int b_lo = qlo / 17, b_hi = qhi / 17;
  int n = 0;
  for (int b = b_lo; b <= b_hi; ++b) {
    const int tfirst = (17 * b) >> 5;
    s[n++] = piece_base(b) + (t - tfirst);
  }
  return n;   // 2 or 3
}

__global__ __launch_bounds__(256) void dot_kernel(
    const float4* __restrict__ P4,
    float* __restrict__ d_acc, u32* __restrict__ d_cnt,
    float* __restrict__ out)
{
  __shared__ float red[4];
  const int tid  = threadIdx.x;
  const int lane = tid & 63;
  const int lt   = blockIdx.x >> 1;
  const int half = blockIdx.x & 1;

  int ti = 0;
  while ((ti + 1) * (ti + 2) / 2 <= lt) ++ti;
  const int tj = lt - ti * (ti + 1) / 2;
  const float w = (ti == tj) ? 1.0f : 2.0f;

  int sx[3], sy[3];
  const int nx = collect_pieces(lt, sx);
  const int ny = collect_pieces(136 + lt, sy);

  const size_t ho = (size_t)half * 2048;
  float s = 0.0f;
#pragma unroll
  for (int j = 0; j < 8; ++j) {
    const int e = tid + j * 256;
    float4 a = P4[(size_t)sx[0] * 4096 + ho + e];
    {
      float4 u = P4[(size_t)sx[1] * 4096 + ho + e];
      a.x += u.x; a.y += u.y; a.z += u.z; a.w += u.w;
    }
    if (nx == 3) {
      float4 u = P4[(size_t)sx[2] * 4096 + ho + e];
      a.x += u.x; a.y += u.y; a.z += u.z; a.w += u.w;
    }
    float4 b = P4[(size_t)sy[0] * 4096 + ho + e];
    {
      float4 u = P4[(size_t)sy[1] * 4096 + ho + e];
      b.x += u.x; b.y += u.y; b.z += u.z; b.w += u.w;
    }
    if (ny == 3) {
      float4 u = P4[(size_t)sy[2] * 4096 + ho + e];
      b.x += u.x; b.y += u.y; b.z += u.z; b.w += u.w;
    }
    s += a.x * b.x + a.y * b.y + a.z * b.z + a.w * b.w;
  }
  s *= w;
#pragma unroll
  for (int off = 32; off > 0; off >>= 1)
    s += __shfl_down(s, off);
  if (lane == 0) red[tid >> 6] = s;
  __syncthreads();
  if (tid == 0) {
    atomicAdd(d_acc, red[0] + red[1] + red[2] + red[3]);
    __threadfence();
    const u32 old = atomicAdd(d_cnt, 1u);
    if (old == 271u) {                     // last of 272 blocks
      float S   = atomicAdd(d_acc, 0.0f);  // device-coherent read
      // fidelity = S / (B^2 * 64^4) = S * 2^-50
      float fid = S * 0x1.0p-50f;
      fid = fminf(fmaxf(fid, 0.0f), 1.0f);
      *out = 0.1f * fabsf(fid - 0.95f);
    }
  }
}

extern "C" void kernel_launch(void* const* d_in, const int* in_sizes, int n_in,
                              void* d_out, int out_size, void* d_ws, size_t ws_size,
                              hipStream_t stream) {
  const float* L = (const float*)d_in[0];
  const float* T = (const float*)d_in[1];
  float* out = (float*)d_out;

  const size_t NF4 = (size_t)BATCH * DIM / 2;    // 8,388,608 B per fp4 tensor
  u8*    X   = (u8*)d_ws;
  u8*    Y   = (u8*)d_ws + NF4;
  float* P   = (float*)((char*)d_ws + 2 * NF4);  // 768 piece slots x 64 KB
  float* acc = P + (size_t)NSLOT * 16384;
  u32*   cnt = (u32*)(acc + 1);

  tcvt_fp4<<<2048, 256, 0, stream>>>(L, T, X, Y, acc, cnt);
  gram_fp4<<<512, 256, 0, stream>>>(X, Y, P);
  dot_kernel<<<272, 256, 0, stream>>>((const float4*)P, acc, cnt, out);
}